// Round 6
// baseline (731.402 us; speedup 1.0000x reference)
//
#include <hip/hip_runtime.h>
#include <stdint.h>

typedef unsigned short u16;
typedef uint32_t u32;
typedef short bf16x8 __attribute__((ext_vector_type(8)));
typedef float f32x4 __attribute__((ext_vector_type(4)));

#define DEV_INLINE __device__ __forceinline__

DEV_INLINE float b2f(u16 u) { union { u32 u; float f; } a; a.u = ((u32)u) << 16; return a.f; }
DEV_INLINE u16 f2b(float f) {
    union { float f; u32 u; } a; a.f = f;
    u32 u = a.u;
    u += 0x7fffu + ((u >> 16) & 1u);
    return (u16)(u >> 16);
}

typedef __attribute__((address_space(1))) u32 as1_u32;
typedef __attribute__((address_space(3))) u32 as3_u32;
DEV_INLINE void async16(void* lds, const void* g) {
    __builtin_amdgcn_global_load_lds((as1_u32*)g, (as3_u32*)lds, 16, 0, 0);
}

#define GP_LGKM()                                         \
    asm volatile("s_waitcnt lgkmcnt(0)" ::: "memory");    \
    __builtin_amdgcn_sched_barrier(0)
#define GP_VW(n)                                          \
    asm volatile("s_waitcnt vmcnt(" #n ")" ::: "memory"); \
    __builtin_amdgcn_sched_barrier(0)
#define GP_BAR() __builtin_amdgcn_s_barrier()

// ---------------------------------------------------------------------------
// gemm_pipe: counted-vmcnt pipelined bf16 GEMM. C = A (M,K) @ B^T, B (N,K) row-major.
// BM=BN=128, BK=32, 256 threads = 4 waves (2M x 2N), per-wave 64x64 — identical
// geometry/fragment map to gemm_bt; ONLY the staging schedule differs.
// STATIC 64 KB LDS: 4-buffer ring, 3 tiles prefetched ahead, vmcnt never drained
// to 0 in the main loop (steady wait = vmcnt(8): tile t+1 landed, 8 loads of
// t+2/t+3 stay in flight).
// Ring safety: iter t+1 overwrites buf[(t+4)&3] = buf[t&3]; every wave's ds_reads
// of buf[t&3] completed at its lgkmcnt(0) before iter t's trailing s_barrier, and
// the overwrite is issued after that barrier.
// vmcnt invariant (4 loads/tile, same issue order in every wave):
//   top of iter t: outstanding = {t+1: 4, t+2: 4} = 8, tile t landed.
//   issue t+3 -> 12; end VW(8) drains 4 oldest = tile t+1.  Tails: VW(4), VW(0).
// Requires: M%128==0, N%128==0, K%32==0, K>=96 (NT>=3).
// ---------------------------------------------------------------------------
template <int MODE>
__global__ __launch_bounds__(256, 2) void gemm_pipe(
    const u16* __restrict__ A, const u16* __restrict__ B, void* __restrict__ Cv,
    int K, long lda, long ldb, long ldc)
{
    __shared__ __align__(16) u16 As[4][128 * 32];
    __shared__ __align__(16) u16 Bs[4][128 * 32];

    int bx = blockIdx.x, by = blockIdx.y;
    {   // XCD-aware bijective swizzle (m204)
        const int gx = gridDim.x, gy = gridDim.y;
        const int nwg = gx * gy;
        const int lin = bx + gx * by;
        const int q = nwg >> 3, r = nwg & 7;
        const int xcd = lin & 7, idx = lin >> 3;
        const int wg = (xcd < r ? xcd * (q + 1) : r * (q + 1) + (xcd - r) * q) + idx;
        bx = wg % gx;
        by = wg / gx;
    }
    const long row0 = (long)by * 128, col0 = (long)bx * 128;

    const int tid = threadIdx.x;
    const int w = tid >> 6, l = tid & 63;
    const int quad = l >> 4, lrow = l & 15;
    const int wm = w & 1, wn = w >> 1;

    f32x4 acc[4][4];
#pragma unroll
    for (int mi = 0; mi < 4; mi++)
#pragma unroll
        for (int ni = 0; ni < 4; ni++) {
            f32x4 zv = {0.f, 0.f, 0.f, 0.f};
            acc[mi][ni] = zv;
        }

    // staging map: thread -> row (tid>>2) of a 64-row unit, 16B chunk (tid&3).
    // Per wave: lds addr = unit_base + lane*16 (linear, as global_load_lds needs).
    const int srow = tid >> 2;
    const int schunk = (tid & 3) * 8;
    const u16* gA = A + (row0 + srow) * lda + schunk;
    const u16* gB = B + (col0 + srow) * ldb + schunk;
    const long a64 = 64 * lda, b64 = 64 * ldb;

#define PSTAGE(bi, kt) do {                                              \
    const long ko_ = (long)(kt) * 32;                                    \
    async16(&As[bi][srow * 32 + schunk], gA + ko_);                      \
    async16(&As[bi][(64 + srow) * 32 + schunk], gA + a64 + ko_);         \
    async16(&Bs[bi][srow * 32 + schunk], gB + ko_);                      \
    async16(&Bs[bi][(64 + srow) * 32 + schunk], gB + b64 + ko_);         \
} while (0)

#define PCOMP(bi)                                                                     \
    bf16x8 af[4], bfr[4];                                                             \
    _Pragma("unroll") for (int i = 0; i < 4; i++)                                     \
        af[i] = *(const bf16x8*)&As[bi][(wm * 64 + i * 16 + lrow) * 32 + quad * 8];   \
    _Pragma("unroll") for (int i = 0; i < 4; i++)                                     \
        bfr[i] = *(const bf16x8*)&Bs[bi][(wn * 64 + i * 16 + lrow) * 32 + quad * 8];  \
    GP_LGKM();                                                                        \
    __builtin_amdgcn_s_setprio(1);                                                    \
    _Pragma("unroll") for (int mi = 0; mi < 4; mi++)                                  \
    _Pragma("unroll") for (int ni = 0; ni < 4; ni++)                                  \
        acc[mi][ni] = __builtin_amdgcn_mfma_f32_16x16x32_bf16(af[mi], bfr[ni], acc[mi][ni], 0, 0, 0); \
    __builtin_amdgcn_s_setprio(0);

    const int NT = K >> 5;  // >= 3

    // prologue: stage tiles 0,1,2
    PSTAGE(0, 0);
    PSTAGE(1, 1);
    PSTAGE(2, 2);
    GP_VW(8);  // tile 0 landed (12 -> 8 outstanding)
    GP_BAR();

    int t = 0;
    for (; t + 3 < NT; ++t) {
        PSTAGE((t + 3) & 3, t + 3);
        { PCOMP(t & 3); }
        GP_VW(8);  // tile t+1 landed; 8 loads (t+2, t+3) stay in flight
        GP_BAR();
    }
    {  // t = NT-3: no issue; drain tile t+1
        { PCOMP(t & 3); }
        GP_VW(4);
        GP_BAR();
        ++t;
    }
    {  // t = NT-2: drain last tile
        { PCOMP(t & 3); }
        GP_VW(0);
        GP_BAR();
        ++t;
    }
    {  // t = NT-1
        { PCOMP(t & 3); }
    }
#undef PSTAGE
#undef PCOMP

    // epilogue: C/D frag mapping col = lane&15, row = quad*4 + reg (same as gemm_bt)
    const long crow = row0 + wm * 64 + quad * 4;
    const long ccol = col0 + wn * 64 + lrow;
    float* Cf = (float*)Cv;
    u16* Cb = (u16*)Cv;
#pragma unroll
    for (int mi = 0; mi < 4; mi++)
#pragma unroll
        for (int rr = 0; rr < 4; rr++) {
            const long r = crow + mi * 16 + rr;
#pragma unroll
            for (int ni = 0; ni < 4; ni++) {
                const long c = ccol + ni * 16;
                const float v = acc[mi][ni][rr];
                if constexpr (MODE == 0) Cf[r * ldc + c] = v;
                else Cb[r * ldc + c] = f2b(v);
            }
        }
}

// ---------------------------------------------------------------------------
// Generic batched bf16 GEMM (2-phase 128x128): C[z] = A[z] @ B[z]^T.
// MODE 0: fp32 store. MODE 1: bf16 store. MODE 2: bf16 store of exp2((acc*scale)*log2e)
//         with causal mask folded (above-diag -> 0). UNNORMALIZED softmax numerator.
// CMASK: skip blocks fully above diagonal. KCAP: K-loop capped at t < row0+128.
// SWZ: XCD-aware bijective swizzle. RSC: MODE-1 epilogue scales row r by rowinv.
// ---------------------------------------------------------------------------
template <int MODE, bool CMASK = false, bool KCAP = false, bool SWZ = false, bool RSC = false>
__global__ __launch_bounds__(256) void gemm_bt(
    const u16* __restrict__ Ab, const u16* __restrict__ Bb, void* __restrict__ Cv,
    int K, long lda, long ldb, long ldc,
    long zA1, long zA2, long zB1, long zB2, long zC1, long zC2,
    float scale, const float* __restrict__ rowinv)
{
    __shared__ __align__(16) u16 As[2][128 * 32];
    __shared__ __align__(16) u16 Bs[2][128 * 32];

    int bx = blockIdx.x, by = blockIdx.y, bz = blockIdx.z;
    if (SWZ) {
        const int gx = gridDim.x, gy = gridDim.y;
        const int nwg = gx * gy * (int)gridDim.z;
        const int lin = bx + gx * (by + gy * bz);
        const int q = nwg >> 3, r = nwg & 7;
        const int xcd = lin & 7, idx = lin >> 3;
        const int wg = (xcd < r ? xcd * (q + 1) : r * (q + 1) + (xcd - r) * q) + idx;
        bx = wg % gx;
        const int t = wg / gx;
        by = t % gy;
        bz = t / gy;
    }

    const long row0 = (long)by * 128;
    const long col0 = (long)bx * 128;
    if (CMASK && col0 > row0) return;

    const long zb = bz >> 5, zh = bz & 31;
    const u16* A = Ab + zb * zA1 + zh * zA2;
    const u16* B = Bb + zb * zB1 + zh * zB2;

    const int tid = threadIdx.x;
    const int w = tid >> 6, l = tid & 63;
    const int quad = l >> 4, lrow = l & 15;
    const int wm = w & 1, wn = w >> 1;

    f32x4 acc[4][4];
#pragma unroll
    for (int mi = 0; mi < 4; mi++)
#pragma unroll
        for (int ni = 0; ni < 4; ni++) {
            f32x4 zv = {0.f, 0.f, 0.f, 0.f};
            acc[mi][ni] = zv;
        }

    const u16* gA = A + (row0 + w * 16 + (l >> 2)) * lda + (l & 3) * 8;
    const u16* gB = B + (col0 + w * 16 + (l >> 2)) * ldb + (l & 3) * 8;
    const int lofs = (w * 16) * 32;
    const long a64 = 64 * lda, b64 = 64 * ldb;

    int nk = K >> 5;
    if (KCAP) {
        const int nkc = (int)(row0 >> 5) + 4;
        nk = nk < nkc ? nk : nkc;
    }

    async16(&As[0][lofs], gA);
    async16(&As[0][lofs + 64 * 32], gA + a64);
    async16(&Bs[0][lofs], gB);
    async16(&Bs[0][lofs + 64 * 32], gB + b64);
    gA += 32;
    gB += 32;

    int cur = 0;
    for (int kt = 0; kt < nk; ++kt) {
        __syncthreads();
        if (kt + 1 < nk) {
            const int nxt = cur ^ 1;
            async16(&As[nxt][lofs], gA);
            async16(&As[nxt][lofs + 64 * 32], gA + a64);
            async16(&Bs[nxt][lofs], gB);
            async16(&Bs[nxt][lofs + 64 * 32], gB + b64);
            gA += 32;
            gB += 32;
        }
        bf16x8 af[4], bfr[4];
#pragma unroll
        for (int i = 0; i < 4; i++)
            af[i] = *(const bf16x8*)&As[cur][(wm * 64 + i * 16 + lrow) * 32 + quad * 8];
#pragma unroll
        for (int i = 0; i < 4; i++)
            bfr[i] = *(const bf16x8*)&Bs[cur][(wn * 64 + i * 16 + lrow) * 32 + quad * 8];
#pragma unroll
        for (int mi = 0; mi < 4; mi++)
#pragma unroll
            for (int ni = 0; ni < 4; ni++)
                acc[mi][ni] = __builtin_amdgcn_mfma_f32_16x16x32_bf16(af[mi], bfr[ni], acc[mi][ni], 0, 0, 0);
        cur ^= 1;
    }

    const long crow = row0 + wm * 64 + quad * 4;
    const long ccol = col0 + wn * 64 + lrow;
    float* Cf = (float*)Cv + zb * zC1 + zh * zC2;
    u16* Cb = (u16*)Cv + zb * zC1 + zh * zC2;
    const float lse = scale * 1.44269504088896f;
#pragma unroll
    for (int mi = 0; mi < 4; mi++)
#pragma unroll
        for (int rr = 0; rr < 4; rr++) {
            const long r = crow + mi * 16 + rr;
            float rs = 1.f;
            if (RSC) rs = rowinv[(long)bz * 1024 + r];
#pragma unroll
            for (int ni = 0; ni < 4; ni++) {
                const long c = ccol + ni * 16;
                const float v = acc[mi][ni][rr];
                if constexpr (MODE == 0) {
                    Cf[r * ldc + c] = v;
                } else if constexpr (MODE == 1) {
                    Cb[r * ldc + c] = f2b(RSC ? v * rs : v);
                } else {
                    const float arg = (c > r) ? -1e30f : v * lse;
                    Cb[r * ldc + c] = f2b(exp2f(arg));
                }
            }
        }
}

// ---------------------------------------------------------------------------
DEV_INLINE float ldval(const float* p) { return *p; }
DEV_INLINE float ldval(const u16* p) { return b2f(*p); }

template <typename SRC>
__global__ __launch_bounds__(256) void transpose_b16(
    const SRC* __restrict__ src, u16* __restrict__ dst,
    int R, int C, long ldS, long ldD, long zS, long zD)
{
    __shared__ float t[32][33];
    src += (long)blockIdx.z * zS;
    dst += (long)blockIdx.z * zD;
    const int tx = threadIdx.x & 31, ty = threadIdx.x >> 5;
    const long c0 = (long)blockIdx.x * 32, r0 = (long)blockIdx.y * 32;
#pragma unroll
    for (int i = 0; i < 4; i++) {
        long r = r0 + ty + i * 8, c = c0 + tx;
        if (r < R && c < C) t[ty + i * 8][tx] = ldval(&src[r * ldS + c]);
    }
    __syncthreads();
#pragma unroll
    for (int i = 0; i < 4; i++) {
        long c = c0 + ty + i * 8, r = r0 + tx;
        if (r < R && c < C) dst[c * ldD + r] = f2b(t[tx][ty + i * 8]);
    }
}

__global__ __launch_bounds__(256) void conv_b16(
    const float* __restrict__ src, u16* __restrict__ dst,
    int C, long ldS, long ldD, long zS, long zD)
{
    const long r = blockIdx.x;
    const float* s = src + (long)blockIdx.z * zS + r * ldS;
    u16* d = dst + (long)blockIdx.z * zD + r * ldD;
    for (int c = threadIdx.x; c < C; c += 256) d[c] = f2b(s[c]);
}

__global__ __launch_bounds__(256) void rmsnorm_b16(
    const float* __restrict__ X, const float* __restrict__ W, u16* __restrict__ Y,
    int C, long ldx, long ldy)
{
    const long r = blockIdx.x;
    const float* x = X + r * ldx;
    u16* y = Y + r * ldy;
    float ss = 0.f;
    for (int c = threadIdx.x; c < C; c += 256) { float v = x[c]; ss += v * v; }
    for (int off = 32; off; off >>= 1) ss += __shfl_down(ss, off);
    __shared__ float red[4];
    if ((threadIdx.x & 63) == 0) red[threadIdx.x >> 6] = ss;
    __syncthreads();
    const float tot = red[0] + red[1] + red[2] + red[3];
    const float inv = rsqrtf(tot / (float)C + 1e-6f);
    for (int c = threadIdx.x; c < C; c += 256) y[c] = f2b(x[c] * inv * W[c]);
}

__global__ __launch_bounds__(256) void rope_k_kernel(
    const float* __restrict__ kv, const float* __restrict__ fc, u16* __restrict__ kcat)
{
    const int idx = blockIdx.x * 256 + threadIdx.x;
    const int n = idx >> 5, i = idx & 31;
    const int s = n & 1023;
    const float e = kv[(long)n * 2176 + 2048 + 2 * i];
    const float o = kv[(long)n * 2176 + 2048 + 2 * i + 1];
    const float cs = fc[s * 64 + 2 * i], sn = fc[s * 64 + 2 * i + 1];
    kcat[(long)n * 576 + 512 + 2 * i] = f2b(e * cs - o * sn);
    kcat[(long)n * 576 + 512 + 2 * i + 1] = f2b(e * sn + o * cs);
}

__global__ __launch_bounds__(256) void rope_q_kernel(
    const u16* __restrict__ q, const float* __restrict__ fc, u16* __restrict__ qcat)
{
    const long idx = (long)blockIdx.x * 256 + threadIdx.x;
    const int i = (int)(idx & 31);
    const long nh = idx >> 5;
    const int h = (int)(nh & 31);
    const long n = nh >> 5;
    const int s = (int)(n & 1023);
    const float e = b2f(q[n * 6144 + h * 192 + 128 + 2 * i]);
    const float o = b2f(q[n * 6144 + h * 192 + 128 + 2 * i + 1]);
    const float cs = fc[s * 64 + 2 * i], sn = fc[s * 64 + 2 * i + 1];
    u16* dst = qcat + ((long)h * 2048 + n) * 576 + 512 + 2 * i;
    dst[0] = f2b(e * cs - o * sn);
    dst[1] = f2b(e * sn + o * cs);
}

// row sums of unnormalized P~ -> inv[z][r] = 1/sum. grid (8, 64).
__global__ __launch_bounds__(256) void rowsum_inv(
    const u16* __restrict__ P, float* __restrict__ inv)
{
    const int zt = blockIdx.y;
    const int row0 = blockIdx.x * 128;
    const int kcap = row0 + 128;
    const int t = threadIdx.x;
    const int r = t >> 1, half = t & 1;
    const u16* p = P + (long)zt * 1048576 + (long)(row0 + r) * 1024;
    float s = 0.f;
    for (int c = half * 8; c < kcap; c += 16) {
        bf16x8 v = *(const bf16x8*)&p[c];
#pragma unroll
        for (int j = 0; j < 8; j++) s += b2f((u16)v[j]);
    }
    s += __shfl_xor(s, 1);
    if (!half) inv[(long)zt * 1024 + row0 + r] = 1.0f / s;
}

__global__ void sentinel_kernel(float* out, float v) { out[0] = v; }

// ---------------------------------------------------------------------------
extern "C" void kernel_launch(void* const* d_in, const int* in_sizes, int n_in,
                              void* d_out, int out_size, void* d_ws, size_t ws_size,
                              hipStream_t stream)
{
    const float* x = (const float*)d_in[0];
    const float* fc = (const float*)d_in[1];
    const float* wq_a = (const float*)d_in[3];
    const float* qnw = (const float*)d_in[4];
    const float* wq_b = (const float*)d_in[5];
    const float* wkva = (const float*)d_in[6];
    const float* kvnw = (const float*)d_in[7];
    const float* wkvb = (const float*)d_in[8];
    const float* wo = (const float*)d_in[9];
    float* out = (float*)d_out;

    const size_t NEED = 252182528ULL;
    if (ws_size < NEED) {
        sentinel_kernel<<<1, 1, 0, stream>>>(out, (float)ws_size);
        return;
    }
    char* ws = (char*)d_ws;
    u16* wkbv   = (u16*)(ws + 0);            // (32,128,512)   4,194,304
    u16* wo_t   = (u16*)(ws + 4194304);      // (4096,4096)   33,554,432
    u16* kvn_t  = (u16*)(ws + 37748736);     // (2,512,1024)   2,097,152
    u16* kcat   = (u16*)(ws + 39845888);     // (2048,576)     2,359,296
    u16* qcat   = (u16*)(ws + 42205184);     // [32 h][2048 n][576] 75,497,472
    u16* o1     = (u16*)(ws + 42205184);     // [32 h][2048 n][512] overlays qcat
    u16* scores = (u16*)(ws + 117702656);    // (2,32,1024,1024) 134,217,728
    u16*   xb     = (u16*)(ws + 117702656);  // (2048,4096)       16,777,216
    u16*   wqkv_t = (u16*)(ws + 134479872);  // (2176,4096)       17,825,792
    u16*   wq_b_t = (u16*)(ws + 152305664);  // (6144,1536)       18,874,368
    u16*   wkbn_t = (u16*)(ws + 171180032);  // (32,512,128)       4,194,304
    float* qk_lat = (float*)(ws + 175374336);// (2048,2176)       17,825,792
    u16*   qn     = (u16*)(ws + 193200128);  // (2048,1536)        6,291,456
    u16*   q      = (u16*)(ws + 199491584);  // (2048,6144)       25,165,824
    u16*   o2     = (u16*)(ws + 117702656);  // (2048,4096) overlays scores
    float* inv_g  = (float*)(ws + 251920384);// (64,1024) fp32      262,144

    const dim3 blk(256);
    const float SCALE = 0.0721687836487032f;  // 192^-0.5

    // ---- weight prep ----
    transpose_b16<float><<<dim3(48, 128, 1), blk, 0, stream>>>(wq_a, wqkv_t, 4096, 1536, 1536, 4096, 0, 0);
    transpose_b16<float><<<dim3(18, 128, 1), blk, 0, stream>>>(wkva, wqkv_t + (long)1536 * 4096, 4096, 576, 576, 4096, 0, 0);
    transpose_b16<float><<<dim3(192, 48, 1), blk, 0, stream>>>(wq_b, wq_b_t, 1536, 6144, 6144, 1536, 0, 0);
    transpose_b16<float><<<dim3(16, 4, 32), blk, 0, stream>>>(wkvb, wkbn_t, 128, 512, 512, 128, 256 * 512, 512 * 128);
    conv_b16<<<dim3(128, 1, 32), blk, 0, stream>>>(wkvb + 128 * 512, wkbv, 512, 512, 512, 256 * 512, 128 * 512);
    transpose_b16<float><<<dim3(128, 128, 1), blk, 0, stream>>>(wo, wo_t, 4096, 4096, 4096, 4096, 0, 0);
    conv_b16<<<dim3(2048, 1, 1), blk, 0, stream>>>(x, xb, 4096, 4096, 4096, 0, 0);

    // ---- s1: qk_lat = xb @ [wq_a | wkv_a]^T : (2048,2176) fp32 ----
    gemm_bt<0, false, false, true><<<dim3(17, 16, 1), blk, 0, stream>>>(
        xb, wqkv_t, qk_lat, 4096, 4096, 4096, 2176, 0, 0, 0, 0, 0, 0, 1.f, nullptr);
    // ---- norms + rope_k + kv transpose ----
    rmsnorm_b16<<<2048, blk, 0, stream>>>(qk_lat, qnw, qn, 1536, 2176, 1536);
    rmsnorm_b16<<<2048, blk, 0, stream>>>(qk_lat + 1536, kvnw, kcat, 512, 2176, 576);
    rope_k_kernel<<<256, blk, 0, stream>>>(qk_lat, fc, kcat);
    transpose_b16<u16><<<dim3(16, 32, 2), blk, 0, stream>>>(kcat, kvn_t, 1024, 512, 576, 1024,
                                                            (long)1024 * 576, (long)512 * 1024);
    // ---- s2: q = qn @ wq_b^T : (2048,6144) bf16  [pipelined, static 64KB LDS] ----
    gemm_pipe<1><<<dim3(48, 16), blk, 0, stream>>>(qn, wq_b_t, q, 1536, 1536, 1536, 6144);
    // ---- s3: qcat[h][:, :512] = q_nope @ wkv_b_nope^T per head (z = h) ----
    gemm_bt<1, false, false, true><<<dim3(4, 16, 32), blk, 0, stream>>>(
        q, wkbn_t, qcat, 128, 6144, 128, 576,
        0, 192, 0, (long)512 * 128, 0, (long)2048 * 576, 1.f, nullptr);
    // ---- rope_q -> qcat[h][:, 512:576] ----
    rope_q_kernel<<<8192, blk, 0, stream>>>(q, fc, qcat);
    // ---- s4: P~ = exp((qcat @ kcat^T)*SCALE + mask), per (b,h) ----
    gemm_bt<2, true, false, true><<<dim3(8, 8, 64), blk, 0, stream>>>(
        qcat, kcat, scores, 576, 576, 576, 1024,
        (long)1024 * 576, (long)2048 * 576, (long)1024 * 576, 0,
        (long)32 * 1048576, 1048576, SCALE, nullptr);
    // ---- row sums -> inv_g ----
    rowsum_inv<<<dim3(8, 64), blk, 0, stream>>>(scores, inv_g);
    // ---- s5: o1 = (P~ @ kv_n) * inv_g[row], K capped ----
    gemm_bt<1, false, true, true, true><<<dim3(4, 8, 64), blk, 0, stream>>>(
        scores, kvn_t, o1, 1024, 1024, 1024, 512,
        (long)32 * 1048576, 1048576, (long)512 * 1024, 0,
        (long)1024 * 512, (long)2048 * 512, 1.f, inv_g);
    // ---- s6: o2 = o1 @ wkv_b_v^T per head ----
    gemm_bt<1, false, false, true><<<dim3(1, 16, 32), blk, 0, stream>>>(
        o1, wkbv, o2, 512, 512, 512, 4096,
        0, (long)2048 * 512, 0, (long)128 * 512, 0, 128, 1.f, nullptr);
    // ---- s7: out = o2 @ wo^T : (2048,4096) fp32  [pipelined, static 64KB LDS] ----
    gemm_pipe<0><<<dim3(32, 16), blk, 0, stream>>>(o2, wo_t, out, 4096, 4096, 4096, 4096);
    (void)in_sizes; (void)n_in; (void)out_size; (void)d_in;
}

// Round 7
// 686.773 us; speedup vs baseline: 1.0650x; 1.0650x over previous
//
#include <hip/hip_runtime.h>
#include <stdint.h>

typedef unsigned short u16;
typedef uint32_t u32;
typedef short bf16x8 __attribute__((ext_vector_type(8)));
typedef float f32x4 __attribute__((ext_vector_type(4)));

#define DEV_INLINE __device__ __forceinline__

DEV_INLINE float b2f(u16 u) { union { u32 u; float f; } a; a.u = ((u32)u) << 16; return a.f; }
DEV_INLINE u16 f2b(float f) {
    union { float f; u32 u; } a; a.f = f;
    u32 u = a.u;
    u += 0x7fffu + ((u >> 16) & 1u);
    return (u16)(u >> 16);
}

typedef __attribute__((address_space(1))) u32 as1_u32;
typedef __attribute__((address_space(3))) u32 as3_u32;
DEV_INLINE void async16(void* lds, const void* g) {
    __builtin_amdgcn_global_load_lds((as1_u32*)g, (as3_u32*)lds, 16, 0, 0);
}

// ---------------------------------------------------------------------------
// gemm_k64: BK=64 bf16 GEMM for GRID-LIMITED stages (<=2 blocks/CU), where the
// 64 KB LDS cost is free and halving the per-iter barrier-drain count is the win.
// C = A (M,K) @ B^T, B (N,K) row-major. BM=BN=128, 256 thr = 4 waves (2M x 2N).
// Same proven 2-phase sync as gemm_bt (one __syncthreads per K-step whose implied
// vmcnt(0)+lgkmcnt(0) drain provides the race-free handoff); 32 MFMA per step.
//
// LDS bank layout (G4): rows are 128 B, so un-swizzled ds_read_b128 column slices
// put all 64 lanes on one 4-bank group (~8x penalty). Fix (rule #21/m173):
// linear LDS dest + inverse-swizzled GLOBAL source + same XOR on the read:
//   slot(r, c16) holds G[r, c16 ^ (r&7)]  =>  read G[r,cn] at slot cn ^ (r&7).
// Balanced: 8 lanes per bank-group x 8 groups = LDS BW floor (8 cy / read wave).
// Requires: M%128==0, N%128==0, K%64==0, K>=128.
// ---------------------------------------------------------------------------
template <int MODE>
__global__ __launch_bounds__(256) void gemm_k64(
    const u16* __restrict__ A, const u16* __restrict__ B, void* __restrict__ Cv,
    int K, long lda, long ldb, long ldc)
{
    __shared__ __align__(16) u16 As[2][128 * 64];
    __shared__ __align__(16) u16 Bs[2][128 * 64];

    int bx = blockIdx.x, by = blockIdx.y;
    {   // XCD-aware bijective swizzle (m204)
        const int gx = gridDim.x, gy = gridDim.y;
        const int nwg = gx * gy;
        const int lin = bx + gx * by;
        const int q = nwg >> 3, r = nwg & 7;
        const int xcd = lin & 7, idx = lin >> 3;
        const int wg = (xcd < r ? xcd * (q + 1) : r * (q + 1) + (xcd - r) * q) + idx;
        bx = wg % gx;
        by = wg / gx;
    }
    const long row0 = (long)by * 128, col0 = (long)bx * 128;

    const int tid = threadIdx.x;
    const int w = tid >> 6, l = tid & 63;
    const int quad = l >> 4, lrow = l & 15;
    const int wm = w & 1, wn = w >> 1;

    f32x4 acc[4][4];
#pragma unroll
    for (int mi = 0; mi < 4; mi++)
#pragma unroll
        for (int ni = 0; ni < 4; ni++) {
            f32x4 zv = {0.f, 0.f, 0.f, 0.f};
            acc[mi][ni] = zv;
        }

    // staging: 4 units of 32 rows per operand; thread -> row (tid>>3) in unit,
    // 16B chunk (tid&7). LDS dest linear per wave (base + lane*16B); global
    // source chunk inverse-swizzled. (row&7) == (srow&7) since units are 32 rows.
    const int srow = tid >> 3;               // 0..31
    const int sch = tid & 7;                 // LDS 16B chunk
    const int gch = sch ^ (srow & 7);        // inverse-swizzled global chunk
    const u16* gA = A + (row0 + srow) * lda + gch * 8;
    const u16* gB = B + (col0 + srow) * ldb + gch * 8;
    const int lofs = srow * 64 + sch * 8;    // element offset, unit 0

#define K64_STAGE(buf, kt) do {                                                   \
    const long ko_ = (long)(kt) * 64;                                             \
    _Pragma("unroll") for (int u = 0; u < 4; ++u) {                               \
        async16(&As[buf][lofs + u * 2048], gA + ko_ + (long)u * 32 * lda);        \
        async16(&Bs[buf][lofs + u * 2048], gB + ko_ + (long)u * 32 * ldb);        \
    } } while (0)

    const int nk = K >> 6;  // >= 2
    K64_STAGE(0, 0);

    int cur = 0;
    for (int kt = 0; kt < nk; ++kt) {
        __syncthreads();  // implied vmcnt(0): buf[cur] staged; lgkmcnt(0): buf[cur^1] reads done
        if (kt + 1 < nk) K64_STAGE(cur ^ 1, kt + 1);
        bf16x8 af[4][2], bfr[4][2];
#pragma unroll
        for (int mi = 0; mi < 4; mi++)
#pragma unroll
            for (int ks = 0; ks < 2; ks++) {
                const int row = wm * 64 + mi * 16 + lrow;
                const int c16 = (ks * 4 + quad) ^ (lrow & 7);  // swizzled read
                af[mi][ks] = *(const bf16x8*)&As[cur][row * 64 + c16 * 8];
            }
#pragma unroll
        for (int ni = 0; ni < 4; ni++)
#pragma unroll
            for (int ks = 0; ks < 2; ks++) {
                const int row = wn * 64 + ni * 16 + lrow;
                const int c16 = (ks * 4 + quad) ^ (lrow & 7);
                bfr[ni][ks] = *(const bf16x8*)&Bs[cur][row * 64 + c16 * 8];
            }
#pragma unroll
        for (int mi = 0; mi < 4; mi++)
#pragma unroll
            for (int ni = 0; ni < 4; ni++)
#pragma unroll
                for (int ks = 0; ks < 2; ks++)
                    acc[mi][ni] = __builtin_amdgcn_mfma_f32_16x16x32_bf16(af[mi][ks], bfr[ni][ks], acc[mi][ni], 0, 0, 0);
        cur ^= 1;
    }
#undef K64_STAGE

    // epilogue: C/D frag mapping col = lane&15, row = quad*4 + reg
    const long crow = row0 + wm * 64 + quad * 4;
    const long ccol = col0 + wn * 64 + lrow;
    float* Cf = (float*)Cv;
    u16* Cb = (u16*)Cv;
#pragma unroll
    for (int mi = 0; mi < 4; mi++)
#pragma unroll
        for (int rr = 0; rr < 4; rr++) {
            const long r = crow + mi * 16 + rr;
#pragma unroll
            for (int ni = 0; ni < 4; ni++) {
                const long c = ccol + ni * 16;
                const float v = acc[mi][ni][rr];
                if constexpr (MODE == 0) Cf[r * ldc + c] = v;
                else Cb[r * ldc + c] = f2b(v);
            }
        }
}

// ---------------------------------------------------------------------------
// Generic batched bf16 GEMM (2-phase 128x128, BK=32): C[z] = A[z] @ B[z]^T.
// MODE 0: fp32 store. MODE 1: bf16 store. MODE 2: bf16 store of exp2((acc*scale)*log2e)
//         with causal mask folded (above-diag -> 0). UNNORMALIZED softmax numerator.
// CMASK: skip blocks fully above diagonal. KCAP: K-loop capped at t < row0+128.
// SWZ: XCD-aware bijective swizzle. RSC: MODE-1 epilogue scales row r by rowinv.
// ---------------------------------------------------------------------------
template <int MODE, bool CMASK = false, bool KCAP = false, bool SWZ = false, bool RSC = false>
__global__ __launch_bounds__(256) void gemm_bt(
    const u16* __restrict__ Ab, const u16* __restrict__ Bb, void* __restrict__ Cv,
    int K, long lda, long ldb, long ldc,
    long zA1, long zA2, long zB1, long zB2, long zC1, long zC2,
    float scale, const float* __restrict__ rowinv)
{
    __shared__ __align__(16) u16 As[2][128 * 32];
    __shared__ __align__(16) u16 Bs[2][128 * 32];

    int bx = blockIdx.x, by = blockIdx.y, bz = blockIdx.z;
    if (SWZ) {
        const int gx = gridDim.x, gy = gridDim.y;
        const int nwg = gx * gy * (int)gridDim.z;
        const int lin = bx + gx * (by + gy * bz);
        const int q = nwg >> 3, r = nwg & 7;
        const int xcd = lin & 7, idx = lin >> 3;
        const int wg = (xcd < r ? xcd * (q + 1) : r * (q + 1) + (xcd - r) * q) + idx;
        bx = wg % gx;
        const int t = wg / gx;
        by = t % gy;
        bz = t / gy;
    }

    const long row0 = (long)by * 128;
    const long col0 = (long)bx * 128;
    if (CMASK && col0 > row0) return;

    const long zb = bz >> 5, zh = bz & 31;
    const u16* A = Ab + zb * zA1 + zh * zA2;
    const u16* B = Bb + zb * zB1 + zh * zB2;

    const int tid = threadIdx.x;
    const int w = tid >> 6, l = tid & 63;
    const int quad = l >> 4, lrow = l & 15;
    const int wm = w & 1, wn = w >> 1;

    f32x4 acc[4][4];
#pragma unroll
    for (int mi = 0; mi < 4; mi++)
#pragma unroll
        for (int ni = 0; ni < 4; ni++) {
            f32x4 zv = {0.f, 0.f, 0.f, 0.f};
            acc[mi][ni] = zv;
        }

    const u16* gA = A + (row0 + w * 16 + (l >> 2)) * lda + (l & 3) * 8;
    const u16* gB = B + (col0 + w * 16 + (l >> 2)) * ldb + (l & 3) * 8;
    const int lofs = (w * 16) * 32;
    const long a64 = 64 * lda, b64 = 64 * ldb;

    int nk = K >> 5;
    if (KCAP) {
        const int nkc = (int)(row0 >> 5) + 4;
        nk = nk < nkc ? nk : nkc;
    }

    async16(&As[0][lofs], gA);
    async16(&As[0][lofs + 64 * 32], gA + a64);
    async16(&Bs[0][lofs], gB);
    async16(&Bs[0][lofs + 64 * 32], gB + b64);
    gA += 32;
    gB += 32;

    int cur = 0;
    for (int kt = 0; kt < nk; ++kt) {
        __syncthreads();
        if (kt + 1 < nk) {
            const int nxt = cur ^ 1;
            async16(&As[nxt][lofs], gA);
            async16(&As[nxt][lofs + 64 * 32], gA + a64);
            async16(&Bs[nxt][lofs], gB);
            async16(&Bs[nxt][lofs + 64 * 32], gB + b64);
            gA += 32;
            gB += 32;
        }
        bf16x8 af[4], bfr[4];
#pragma unroll
        for (int i = 0; i < 4; i++)
            af[i] = *(const bf16x8*)&As[cur][(wm * 64 + i * 16 + lrow) * 32 + quad * 8];
#pragma unroll
        for (int i = 0; i < 4; i++)
            bfr[i] = *(const bf16x8*)&Bs[cur][(wn * 64 + i * 16 + lrow) * 32 + quad * 8];
#pragma unroll
        for (int mi = 0; mi < 4; mi++)
#pragma unroll
            for (int ni = 0; ni < 4; ni++)
                acc[mi][ni] = __builtin_amdgcn_mfma_f32_16x16x32_bf16(af[mi], bfr[ni], acc[mi][ni], 0, 0, 0);
        cur ^= 1;
    }

    const long crow = row0 + wm * 64 + quad * 4;
    const long ccol = col0 + wn * 64 + lrow;
    float* Cf = (float*)Cv + zb * zC1 + zh * zC2;
    u16* Cb = (u16*)Cv + zb * zC1 + zh * zC2;
    const float lse = scale * 1.44269504088896f;
#pragma unroll
    for (int mi = 0; mi < 4; mi++)
#pragma unroll
        for (int rr = 0; rr < 4; rr++) {
            const long r = crow + mi * 16 + rr;
            float rs = 1.f;
            if (RSC) rs = rowinv[(long)bz * 1024 + r];
#pragma unroll
            for (int ni = 0; ni < 4; ni++) {
                const long c = ccol + ni * 16;
                const float v = acc[mi][ni][rr];
                if constexpr (MODE == 0) {
                    Cf[r * ldc + c] = v;
                } else if constexpr (MODE == 1) {
                    Cb[r * ldc + c] = f2b(RSC ? v * rs : v);
                } else {
                    const float arg = (c > r) ? -1e30f : v * lse;
                    Cb[r * ldc + c] = f2b(exp2f(arg));
                }
            }
        }
}

// ---------------------------------------------------------------------------
DEV_INLINE float ldval(const float* p) { return *p; }
DEV_INLINE float ldval(const u16* p) { return b2f(*p); }

template <typename SRC>
__global__ __launch_bounds__(256) void transpose_b16(
    const SRC* __restrict__ src, u16* __restrict__ dst,
    int R, int C, long ldS, long ldD, long zS, long zD)
{
    __shared__ float t[32][33];
    src += (long)blockIdx.z * zS;
    dst += (long)blockIdx.z * zD;
    const int tx = threadIdx.x & 31, ty = threadIdx.x >> 5;
    const long c0 = (long)blockIdx.x * 32, r0 = (long)blockIdx.y * 32;
#pragma unroll
    for (int i = 0; i < 4; i++) {
        long r = r0 + ty + i * 8, c = c0 + tx;
        if (r < R && c < C) t[ty + i * 8][tx] = ldval(&src[r * ldS + c]);
    }
    __syncthreads();
#pragma unroll
    for (int i = 0; i < 4; i++) {
        long c = c0 + ty + i * 8, r = r0 + tx;
        if (r < R && c < C) dst[c * ldD + r] = f2b(t[tx][ty + i * 8]);
    }
}

__global__ __launch_bounds__(256) void conv_b16(
    const float* __restrict__ src, u16* __restrict__ dst,
    int C, long ldS, long ldD, long zS, long zD)
{
    const long r = blockIdx.x;
    const float* s = src + (long)blockIdx.z * zS + r * ldS;
    u16* d = dst + (long)blockIdx.z * zD + r * ldD;
    for (int c = threadIdx.x; c < C; c += 256) d[c] = f2b(s[c]);
}

__global__ __launch_bounds__(256) void rmsnorm_b16(
    const float* __restrict__ X, const float* __restrict__ W, u16* __restrict__ Y,
    int C, long ldx, long ldy)
{
    const long r = blockIdx.x;
    const float* x = X + r * ldx;
    u16* y = Y + r * ldy;
    float ss = 0.f;
    for (int c = threadIdx.x; c < C; c += 256) { float v = x[c]; ss += v * v; }
    for (int off = 32; off; off >>= 1) ss += __shfl_down(ss, off);
    __shared__ float red[4];
    if ((threadIdx.x & 63) == 0) red[threadIdx.x >> 6] = ss;
    __syncthreads();
    const float tot = red[0] + red[1] + red[2] + red[3];
    const float inv = rsqrtf(tot / (float)C + 1e-6f);
    for (int c = threadIdx.x; c < C; c += 256) y[c] = f2b(x[c] * inv * W[c]);
}

__global__ __launch_bounds__(256) void rope_k_kernel(
    const float* __restrict__ kv, const float* __restrict__ fc, u16* __restrict__ kcat)
{
    const int idx = blockIdx.x * 256 + threadIdx.x;
    const int n = idx >> 5, i = idx & 31;
    const int s = n & 1023;
    const float e = kv[(long)n * 2176 + 2048 + 2 * i];
    const float o = kv[(long)n * 2176 + 2048 + 2 * i + 1];
    const float cs = fc[s * 64 + 2 * i], sn = fc[s * 64 + 2 * i + 1];
    kcat[(long)n * 576 + 512 + 2 * i] = f2b(e * cs - o * sn);
    kcat[(long)n * 576 + 512 + 2 * i + 1] = f2b(e * sn + o * cs);
}

__global__ __launch_bounds__(256) void rope_q_kernel(
    const u16* __restrict__ q, const float* __restrict__ fc, u16* __restrict__ qcat)
{
    const long idx = (long)blockIdx.x * 256 + threadIdx.x;
    const int i = (int)(idx & 31);
    const long nh = idx >> 5;
    const int h = (int)(nh & 31);
    const long n = nh >> 5;
    const int s = (int)(n & 1023);
    const float e = b2f(q[n * 6144 + h * 192 + 128 + 2 * i]);
    const float o = b2f(q[n * 6144 + h * 192 + 128 + 2 * i + 1]);
    const float cs = fc[s * 64 + 2 * i], sn = fc[s * 64 + 2 * i + 1];
    u16* dst = qcat + ((long)h * 2048 + n) * 576 + 512 + 2 * i;
    dst[0] = f2b(e * cs - o * sn);
    dst[1] = f2b(e * sn + o * cs);
}

// row sums of unnormalized P~ -> inv[z][r] = 1/sum. grid (8, 64).
__global__ __launch_bounds__(256) void rowsum_inv(
    const u16* __restrict__ P, float* __restrict__ inv)
{
    const int zt = blockIdx.y;
    const int row0 = blockIdx.x * 128;
    const int kcap = row0 + 128;
    const int t = threadIdx.x;
    const int r = t >> 1, half = t & 1;
    const u16* p = P + (long)zt * 1048576 + (long)(row0 + r) * 1024;
    float s = 0.f;
    for (int c = half * 8; c < kcap; c += 16) {
        bf16x8 v = *(const bf16x8*)&p[c];
#pragma unroll
        for (int j = 0; j < 8; j++) s += b2f((u16)v[j]);
    }
    s += __shfl_xor(s, 1);
    if (!half) inv[(long)zt * 1024 + row0 + r] = 1.0f / s;
}

__global__ void sentinel_kernel(float* out, float v) { out[0] = v; }

// ---------------------------------------------------------------------------
extern "C" void kernel_launch(void* const* d_in, const int* in_sizes, int n_in,
                              void* d_out, int out_size, void* d_ws, size_t ws_size,
                              hipStream_t stream)
{
    const float* x = (const float*)d_in[0];
    const float* fc = (const float*)d_in[1];
    const float* wq_a = (const float*)d_in[3];
    const float* qnw = (const float*)d_in[4];
    const float* wq_b = (const float*)d_in[5];
    const float* wkva = (const float*)d_in[6];
    const float* kvnw = (const float*)d_in[7];
    const float* wkvb = (const float*)d_in[8];
    const float* wo = (const float*)d_in[9];
    float* out = (float*)d_out;

    const size_t NEED = 252182528ULL;
    if (ws_size < NEED) {
        sentinel_kernel<<<1, 1, 0, stream>>>(out, (float)ws_size);
        return;
    }
    char* ws = (char*)d_ws;
    u16* wkbv   = (u16*)(ws + 0);            // (32,128,512)   4,194,304
    u16* wo_t   = (u16*)(ws + 4194304);      // (4096,4096)   33,554,432
    u16* kvn_t  = (u16*)(ws + 37748736);     // (2,512,1024)   2,097,152
    u16* kcat   = (u16*)(ws + 39845888);     // (2048,576)     2,359,296
    u16* qcat   = (u16*)(ws + 42205184);     // [32 h][2048 n][576] 75,497,472
    u16* o1     = (u16*)(ws + 42205184);     // [32 h][2048 n][512] overlays qcat
    u16* scores = (u16*)(ws + 117702656);    // (2,32,1024,1024) 134,217,728
    u16*   xb     = (u16*)(ws + 117702656);  // (2048,4096)       16,777,216
    u16*   wqkv_t = (u16*)(ws + 134479872);  // (2176,4096)       17,825,792
    u16*   wq_b_t = (u16*)(ws + 152305664);  // (6144,1536)       18,874,368
    u16*   wkbn_t = (u16*)(ws + 171180032);  // (32,512,128)       4,194,304
    float* qk_lat = (float*)(ws + 175374336);// (2048,2176)       17,825,792
    u16*   qn     = (u16*)(ws + 193200128);  // (2048,1536)        6,291,456
    u16*   q      = (u16*)(ws + 199491584);  // (2048,6144)       25,165,824
    u16*   o2     = (u16*)(ws + 117702656);  // (2048,4096) overlays scores
    float* inv_g  = (float*)(ws + 251920384);// (64,1024) fp32      262,144

    const dim3 blk(256);
    const float SCALE = 0.0721687836487032f;  // 192^-0.5

    // ---- weight prep ----
    transpose_b16<float><<<dim3(48, 128, 1), blk, 0, stream>>>(wq_a, wqkv_t, 4096, 1536, 1536, 4096, 0, 0);
    transpose_b16<float><<<dim3(18, 128, 1), blk, 0, stream>>>(wkva, wqkv_t + (long)1536 * 4096, 4096, 576, 576, 4096, 0, 0);
    transpose_b16<float><<<dim3(192, 48, 1), blk, 0, stream>>>(wq_b, wq_b_t, 1536, 6144, 6144, 1536, 0, 0);
    transpose_b16<float><<<dim3(16, 4, 32), blk, 0, stream>>>(wkvb, wkbn_t, 128, 512, 512, 128, 256 * 512, 512 * 128);
    conv_b16<<<dim3(128, 1, 32), blk, 0, stream>>>(wkvb + 128 * 512, wkbv, 512, 512, 512, 256 * 512, 128 * 512);
    transpose_b16<float><<<dim3(128, 128, 1), blk, 0, stream>>>(wo, wo_t, 4096, 4096, 4096, 4096, 0, 0);
    conv_b16<<<dim3(2048, 1, 1), blk, 0, stream>>>(x, xb, 4096, 4096, 4096, 0, 0);

    // ---- s1: qk_lat = xb @ [wq_a | wkv_a]^T : (2048,2176) fp32  [BK=64 kernel] ----
    gemm_k64<0><<<dim3(17, 16), blk, 0, stream>>>(xb, wqkv_t, qk_lat, 4096, 4096, 4096, 2176);
    // ---- norms + rope_k + kv transpose ----
    rmsnorm_b16<<<2048, blk, 0, stream>>>(qk_lat, qnw, qn, 1536, 2176, 1536);
    rmsnorm_b16<<<2048, blk, 0, stream>>>(qk_lat + 1536, kvnw, kcat, 512, 2176, 576);
    rope_k_kernel<<<256, blk, 0, stream>>>(qk_lat, fc, kcat);
    transpose_b16<u16><<<dim3(16, 32, 2), blk, 0, stream>>>(kcat, kvn_t, 1024, 512, 576, 1024,
                                                            (long)1024 * 576, (long)512 * 1024);
    // ---- s2: q = qn @ wq_b^T : (2048,6144) bf16  [proven 2-phase, 3 blocks/CU] ----
    gemm_bt<1, false, false, true><<<dim3(48, 16, 1), blk, 0, stream>>>(
        qn, wq_b_t, q, 1536, 1536, 1536, 6144, 0, 0, 0, 0, 0, 0, 1.f, nullptr);
    // ---- s3: qcat[h][:, :512] = q_nope @ wkv_b_nope^T per head (z = h) ----
    gemm_bt<1, false, false, true><<<dim3(4, 16, 32), blk, 0, stream>>>(
        q, wkbn_t, qcat, 128, 6144, 128, 576,
        0, 192, 0, (long)512 * 128, 0, (long)2048 * 576, 1.f, nullptr);
    // ---- rope_q -> qcat[h][:, 512:576] ----
    rope_q_kernel<<<8192, blk, 0, stream>>>(q, fc, qcat);
    // ---- s4: P~ = exp((qcat @ kcat^T)*SCALE + mask), per (b,h) ----
    gemm_bt<2, true, false, true><<<dim3(8, 8, 64), blk, 0, stream>>>(
        qcat, kcat, scores, 576, 576, 576, 1024,
        (long)1024 * 576, (long)2048 * 576, (long)1024 * 576, 0,
        (long)32 * 1048576, 1048576, SCALE, nullptr);
    // ---- row sums -> inv_g ----
    rowsum_inv<<<dim3(8, 64), blk, 0, stream>>>(scores, inv_g);
    // ---- s5: o1 = (P~ @ kv_n) * inv_g[row], K capped ----
    gemm_bt<1, false, true, true, true><<<dim3(4, 8, 64), blk, 0, stream>>>(
        scores, kvn_t, o1, 1024, 1024, 1024, 512,
        (long)32 * 1048576, 1048576, (long)512 * 1024, 0,
        (long)1024 * 512, (long)2048 * 512, 1.f, inv_g);
    // ---- s6: o2 = o1 @ wkv_b_v^T per head ----
    gemm_bt<1, false, false, true><<<dim3(1, 16, 32), blk, 0, stream>>>(
        o1, wkbv, o2, 512, 512, 512, 4096,
        0, (long)2048 * 512, 0, (long)128 * 512, 0, 128, 1.f, nullptr);
    // ---- s7: out = o2 @ wo^T : (2048,4096) fp32  [BK=64 kernel] ----
    gemm_k64<0><<<dim3(32, 16), blk, 0, stream>>>(o2, wo_t, out, 4096, 4096, 4096, 4096);
    (void)in_sizes; (void)n_in; (void)out_size; (void)d_in;
}